// Round 1
// 1156.950 us; speedup vs baseline: 1.0636x; 1.0636x over previous
//
#include <hip/hip_runtime.h>
#include <stdint.h>

// Problem constants (B=4,S=2048 -> T=8192)
#define T_TOK 8192
#define H_DIM 1024
#define F_DIM 3584
#define E_NUM 8

// GEMM tiling
#define BM 128
#define BN 128
#define BK 32

typedef __attribute__((ext_vector_type(8))) short bf16x8;
typedef __attribute__((ext_vector_type(4))) float f32x4;
typedef __attribute__((ext_vector_type(4))) uint32_t u32x4;

typedef const __attribute__((address_space(1))) void gv_t;
typedef __attribute__((address_space(3))) void lv_t;

// Async global->LDS, 16B per lane. LDS dest is wave-uniform base + lane*16.
#define GLOAD_LDS16(g, l) \
    __builtin_amdgcn_global_load_lds((gv_t*)(g), (lv_t*)(l), 16, 0, 0)

__device__ __forceinline__ short f2bf(float f) {
    union { float f; uint32_t u; } v; v.f = f;
    uint32_t r = v.u + 0x7fffu + ((v.u >> 16) & 1u);   // RNE bf16
    return (short)(r >> 16);
}

// Pack 2 fp32 -> bf16x2 in ~3 VALU ops via v_perm_b32 (same rounding as the
// previous per-tile staging path -> bitwise-identical GEMM inputs).
__device__ __forceinline__ uint32_t pack_bf16x2(float a, float b) {
    union { float f; uint32_t u; } ua, ub;
    ua.f = a; ub.f = b;
    return __builtin_amdgcn_perm(ub.u + 0x8000u, ua.u + 0x8000u, 0x07060302u);
}

// ---------------------------------------------------------------------------
// One-shot fp32 -> bf16 conversion of w1, w3, w2, x into workspace.
// Streaming, 8 elems/thread/iter (32B read, 16B write).
// ---------------------------------------------------------------------------
__global__ __launch_bounds__(256)
void cvt4_kernel(const float* __restrict__ w1, const float* __restrict__ w3,
                 const float* __restrict__ w2, const float* __restrict__ x,
                 unsigned short* __restrict__ w1b, unsigned short* __restrict__ w3b,
                 unsigned short* __restrict__ w2b, unsigned short* __restrict__ xb) {
    const int z = blockIdx.z;
    const float* src; unsigned short* dst; int n8;
    if (z == 0)      { src = w1; dst = w1b; n8 = (E_NUM * F_DIM * H_DIM) / 8; }
    else if (z == 1) { src = w3; dst = w3b; n8 = (E_NUM * F_DIM * H_DIM) / 8; }
    else if (z == 2) { src = w2; dst = w2b; n8 = (E_NUM * H_DIM * F_DIM) / 8; }
    else             { src = x;  dst = xb;  n8 = (T_TOK * H_DIM) / 8; }

    int idx = blockIdx.x * blockDim.x + threadIdx.x;
    int stride = gridDim.x * blockDim.x;
    for (int i = idx; i < n8; i += stride) {
        const f32x4* p = (const f32x4*)src + (size_t)i * 2;
        f32x4 v0 = p[0], v1 = p[1];
        u32x4 w;
        w[0] = pack_bf16x2(v0[0], v0[1]);
        w[1] = pack_bf16x2(v0[2], v0[3]);
        w[2] = pack_bf16x2(v1[0], v1[1]);
        w[3] = pack_bf16x2(v1[2], v1[3]);
        ((u32x4*)dst)[i] = w;
    }
}

// ---------------------------------------------------------------------------
// Router: one wave per token. fp32 logits (exact), top-2, normalized weights,
// append assignment id a=2t+k to per-expert list.
// ---------------------------------------------------------------------------
__global__ void router_kernel(const float* __restrict__ x,
                              const float* __restrict__ gate_w,
                              float* __restrict__ logits_out,
                              int* __restrict__ counts,
                              int* __restrict__ lists,
                              float* __restrict__ wgt) {
    int wave = (blockIdx.x * blockDim.x + threadIdx.x) >> 6;
    int lane = threadIdx.x & 63;
    if (wave >= T_TOK) return;
    const float* xr = x + (size_t)wave * H_DIM;

    float acc[E_NUM];
    #pragma unroll
    for (int e = 0; e < E_NUM; e++) acc[e] = 0.f;

    for (int i = lane; i < H_DIM; i += 64) {
        float xv = xr[i];
        #pragma unroll
        for (int e = 0; e < E_NUM; e++) acc[e] += xv * gate_w[e * H_DIM + i];
    }
    #pragma unroll
    for (int off = 32; off > 0; off >>= 1) {
        #pragma unroll
        for (int e = 0; e < E_NUM; e++) acc[e] += __shfl_xor(acc[e], off);
    }

    if (lane == 0) {
        int t = wave;
        #pragma unroll
        for (int e = 0; e < E_NUM; e++) logits_out[t * E_NUM + e] = acc[e];
        int i0 = 0; float v0 = acc[0];
        #pragma unroll
        for (int e = 1; e < E_NUM; e++) if (acc[e] > v0) { v0 = acc[e]; i0 = e; }
        int i1 = -1; float v1 = -1e30f;
        #pragma unroll
        for (int e = 0; e < E_NUM; e++) if (e != i0 && acc[e] > v1) { v1 = acc[e]; i1 = e; }
        float e1 = __expf(v1 - v0);
        float inv = 1.f / (1.f + e1);
        int a0 = 2 * t, a1 = 2 * t + 1;
        wgt[a0] = inv;
        wgt[a1] = e1 * inv;
        int p0 = atomicAdd(&counts[i0], 1);
        lists[i0 * T_TOK + p0] = a0;
        int p1 = atomicAdd(&counts[i1], 1);
        lists[i1 * T_TOK + p1] = a1;
    }
}

// ---------------------------------------------------------------------------
// GEMM1: hgate = silu(x @ w1[e]^T) * (x @ w3[e]^T), gathered token rows.
// bf16 inputs; global_load_lds direct staging; double-buffered 2-phase loop
// (stage k+1 issued before MFMA of k, single barrier per K-step).
// LDS layout is linear [row][BK] (rule #21: no swizzle on either side).
// ---------------------------------------------------------------------------
__global__ __launch_bounds__(256, 2)
void gemm1_kernel(const unsigned short* __restrict__ xb,
                  const unsigned short* __restrict__ w1b,
                  const unsigned short* __restrict__ w3b,
                  const int* __restrict__ counts,
                  const int* __restrict__ lists,
                  unsigned short* __restrict__ hgate) {
    const int e = blockIdx.z;
    const int count = counts[e];
    const int mbase = blockIdx.y * BM;
    if (mbase >= count) return;
    const int nbase = blockIdx.x * BN;

    __shared__ short As[2][BM * BK];    // 8KB per buffer
    __shared__ short B1s[2][BM * BK];
    __shared__ short B3s[2][BM * BK];

    const int tid = threadIdx.x;
    const int lane = tid & 63;
    const int wid = tid >> 6;
    const int wm = wid >> 1, wn = wid & 1;
    const int lr = lane & 15, lq = lane >> 4;

    // Staging geometry: wave wid covers rows 32*wid..32*wid+31 (two 16-row
    // 1KB chunks). Lane l: row = chunk*16 + (l>>2), k-bytes (l&3)*16.
    const int srow0 = wid * 32 + (lane >> 2);
    const int srow1 = srow0 + 16;
    const int kp8 = (lane & 3) * 8;          // k offset in elems

    const unsigned short *ag0, *ag1;
    {
        int m0 = mbase + srow0; if (m0 >= count) m0 = count - 1;
        int m1 = mbase + srow1; if (m1 >= count) m1 = count - 1;
        ag0 = xb + (size_t)(lists[e * T_TOK + m0] >> 1) * H_DIM + kp8;
        ag1 = xb + (size_t)(lists[e * T_TOK + m1] >> 1) * H_DIM + kp8;
    }
    const unsigned short* b1g0 = w1b + ((size_t)e * F_DIM + nbase + srow0) * H_DIM + kp8;
    const unsigned short* b1g1 = b1g0 + (size_t)16 * H_DIM;
    const unsigned short* b3g0 = w3b + ((size_t)e * F_DIM + nbase + srow0) * H_DIM + kp8;
    const unsigned short* b3g1 = b3g0 + (size_t)16 * H_DIM;

    const int ldsc = wid * 1024;             // wave's chunk base (elems)

    auto stage = [&](int buf) {
        GLOAD_LDS16(ag0,  &As[buf][ldsc]);
        GLOAD_LDS16(ag1,  &As[buf][ldsc + 512]);
        GLOAD_LDS16(b1g0, &B1s[buf][ldsc]);
        GLOAD_LDS16(b1g1, &B1s[buf][ldsc + 512]);
        GLOAD_LDS16(b3g0, &B3s[buf][ldsc]);
        GLOAD_LDS16(b3g1, &B3s[buf][ldsc + 512]);
        ag0 += BK; ag1 += BK;
        b1g0 += BK; b1g1 += BK;
        b3g0 += BK; b3g1 += BK;
    };

    f32x4 acc1[4][4], acc3[4][4];
    #pragma unroll
    for (int i = 0; i < 4; i++)
        #pragma unroll
        for (int j = 0; j < 4; j++) {
            acc1[i][j] = (f32x4){0.f, 0.f, 0.f, 0.f};
            acc3[i][j] = (f32x4){0.f, 0.f, 0.f, 0.f};
        }

    stage(0);
    __syncthreads();                         // buf0 landed (vmcnt drained)

    const int NK = H_DIM / BK;               // 32
    for (int kt = 0; kt < NK; ++kt) {
        const int cur = kt & 1;
        if (kt + 1 < NK) stage(cur ^ 1);     // prefetch next tile (async)

        bf16x8 af[4], b1f[4], b3f[4];
        #pragma unroll
        for (int i = 0; i < 4; i++)
            af[i] = *(const bf16x8*)&As[cur][(wm * 64 + i * 16 + lr) * BK + lq * 8];
        #pragma unroll
        for (int j = 0; j < 4; j++) {
            b1f[j] = *(const bf16x8*)&B1s[cur][(wn * 64 + j * 16 + lr) * BK + lq * 8];
            b3f[j] = *(const bf16x8*)&B3s[cur][(wn * 64 + j * 16 + lr) * BK + lq * 8];
        }
        #pragma unroll
        for (int i = 0; i < 4; i++)
            #pragma unroll
            for (int j = 0; j < 4; j++) {
                acc1[i][j] = __builtin_amdgcn_mfma_f32_16x16x32_bf16(af[i], b1f[j], acc1[i][j], 0, 0, 0);
                acc3[i][j] = __builtin_amdgcn_mfma_f32_16x16x32_bf16(af[i], b3f[j], acc3[i][j], 0, 0, 0);
            }
        __syncthreads();                     // drains vmcnt -> next buf ready
    }

    // Epilogue: silu(g)*u -> bf16, scatter rows by assignment id.
    // C/D layout: col = lane&15, row(within 16) = (lane>>4)*4 + reg
    #pragma unroll
    for (int i = 0; i < 4; i++) {
        #pragma unroll
        for (int rg = 0; rg < 4; rg++) {
            int mm = mbase + wm * 64 + i * 16 + lq * 4 + rg;
            if (mm >= count) continue;
            int a = lists[e * T_TOK + mm];
            unsigned short* hrow = hgate + (size_t)a * F_DIM + nbase;
            #pragma unroll
            for (int j = 0; j < 4; j++) {
                float g = acc1[i][j][rg];
                float u = acc3[i][j][rg];
                float s = (g / (1.f + __expf(-g))) * u;
                hrow[wn * 64 + j * 16 + lr] = (unsigned short)f2bf(s);
            }
        }
    }
}

// ---------------------------------------------------------------------------
// GEMM2: out[t] += weight * (hgate_row @ w2[e]^T). Both operands bf16,
// global_load_lds staging, double-buffered 2-phase. fp32 atomicAdd scatter.
// ---------------------------------------------------------------------------
__global__ __launch_bounds__(256, 2)
void gemm2_kernel(const unsigned short* __restrict__ hgate,
                  const unsigned short* __restrict__ w2b,
                  const int* __restrict__ counts,
                  const int* __restrict__ lists,
                  const float* __restrict__ wgt,
                  float* __restrict__ out) {
    const int e = blockIdx.z;
    const int count = counts[e];
    const int mbase = blockIdx.y * BM;
    if (mbase >= count) return;
    const int nbase = blockIdx.x * BN;

    __shared__ short As[2][BM * BK];
    __shared__ short Bs[2][BM * BK];

    const int tid = threadIdx.x;
    const int lane = tid & 63;
    const int wid = tid >> 6;
    const int wm = wid >> 1, wn = wid & 1;
    const int lr = lane & 15, lq = lane >> 4;

    const int srow0 = wid * 32 + (lane >> 2);
    const int srow1 = srow0 + 16;
    const int kp8 = (lane & 3) * 8;

    const unsigned short *ag0, *ag1;
    {
        int m0 = mbase + srow0; if (m0 >= count) m0 = count - 1;
        int m1 = mbase + srow1; if (m1 >= count) m1 = count - 1;
        ag0 = hgate + (size_t)lists[e * T_TOK + m0] * F_DIM + kp8;
        ag1 = hgate + (size_t)lists[e * T_TOK + m1] * F_DIM + kp8;
    }
    const unsigned short* bg0 = w2b + ((size_t)e * H_DIM + nbase + srow0) * F_DIM + kp8;
    const unsigned short* bg1 = bg0 + (size_t)16 * F_DIM;

    const int ldsc = wid * 1024;

    auto stage = [&](int buf) {
        GLOAD_LDS16(ag0, &As[buf][ldsc]);
        GLOAD_LDS16(ag1, &As[buf][ldsc + 512]);
        GLOAD_LDS16(bg0, &Bs[buf][ldsc]);
        GLOAD_LDS16(bg1, &Bs[buf][ldsc + 512]);
        ag0 += BK; ag1 += BK;
        bg0 += BK; bg1 += BK;
    };

    f32x4 acc[4][4];
    #pragma unroll
    for (int i = 0; i < 4; i++)
        #pragma unroll
        for (int j = 0; j < 4; j++) acc[i][j] = (f32x4){0.f, 0.f, 0.f, 0.f};

    stage(0);
    __syncthreads();

    const int NK = F_DIM / BK;               // 112
    for (int kt = 0; kt < NK; ++kt) {
        const int cur = kt & 1;
        if (kt + 1 < NK) stage(cur ^ 1);

        bf16x8 af[4], bfr[4];
        #pragma unroll
        for (int i = 0; i < 4; i++)
            af[i] = *(const bf16x8*)&As[cur][(wm * 64 + i * 16 + lr) * BK + lq * 8];
        #pragma unroll
        for (int j = 0; j < 4; j++)
            bfr[j] = *(const bf16x8*)&Bs[cur][(wn * 64 + j * 16 + lr) * BK + lq * 8];
        #pragma unroll
        for (int i = 0; i < 4; i++)
            #pragma unroll
            for (int j = 0; j < 4; j++)
                acc[i][j] = __builtin_amdgcn_mfma_f32_16x16x32_bf16(af[i], bfr[j], acc[i][j], 0, 0, 0);
        __syncthreads();
    }

    #pragma unroll
    for (int i = 0; i < 4; i++) {
        #pragma unroll
        for (int rg = 0; rg < 4; rg++) {
            int mm = mbase + wm * 64 + i * 16 + lq * 4 + rg;
            if (mm >= count) continue;
            int a = lists[e * T_TOK + mm];
            float w = wgt[a];
            int t = a >> 1;
            float* orow = out + (size_t)t * H_DIM + nbase;
            #pragma unroll
            for (int j = 0; j < 4; j++)
                atomicAdd(&orow[wn * 64 + j * 16 + lr], acc[i][j][rg] * w);
        }
    }
}

// ---------------------------------------------------------------------------
extern "C" void kernel_launch(void* const* d_in, const int* in_sizes, int n_in,
                              void* d_out, int out_size, void* d_ws, size_t ws_size,
                              hipStream_t stream) {
    const float* x      = (const float*)d_in[0];  // [T, H]
    const float* gate_w = (const float*)d_in[1];  // [E, H]
    const float* w1     = (const float*)d_in[2];  // [E, F, H]
    const float* w2     = (const float*)d_in[3];  // [E, H, F]
    const float* w3     = (const float*)d_in[4];  // [E, F, H]

    float* out    = (float*)d_out;                      // [T, H]
    float* logits = out + (size_t)T_TOK * H_DIM;        // [T, E]

    // ws layout: counts[8](pad 1KB) | lists[E][T] | wgt[2T] | hgate[2T][F] bf16
    //            | xb[T][H] bf16 | w1b | w3b | w2b      (total ~311 MB)
    char* ws = (char*)d_ws;
    int*   counts = (int*)(ws + 0);
    int*   lists  = (int*)(ws + 1024);
    float* wgt    = (float*)(ws + 1024 + (size_t)E_NUM * T_TOK * 4);
    unsigned short* hgate =
        (unsigned short*)(ws + 1024 + (size_t)E_NUM * T_TOK * 4 + (size_t)T_TOK * 2 * 4);
    unsigned short* xb  = hgate + (size_t)2 * T_TOK * F_DIM;
    unsigned short* w1b = xb + (size_t)T_TOK * H_DIM;
    unsigned short* w3b = w1b + (size_t)E_NUM * F_DIM * H_DIM;
    unsigned short* w2b = w3b + (size_t)E_NUM * F_DIM * H_DIM;

    hipMemsetAsync(counts, 0, E_NUM * sizeof(int), stream);
    hipMemsetAsync(out, 0, (size_t)T_TOK * H_DIM * sizeof(float), stream);

    cvt4_kernel<<<dim3(1024, 1, 4), 256, 0, stream>>>(w1, w3, w2, x, w1b, w3b, w2b, xb);

    router_kernel<<<T_TOK / 4, 256, 0, stream>>>(x, gate_w, logits, counts, lists, wgt);

    gemm1_kernel<<<dim3(F_DIM / BN, T_TOK / BM, E_NUM), 256, 0, stream>>>(
        xb, w1b, w3b, counts, lists, hgate);

    gemm2_kernel<<<dim3(H_DIM / BN, T_TOK / BM, E_NUM), 256, 0, stream>>>(
        hgate, w2b, counts, lists, wgt, out);
}

// Round 2
// 1135.167 us; speedup vs baseline: 1.0840x; 1.0192x over previous
//
#include <hip/hip_runtime.h>
#include <stdint.h>

// Problem constants (B=4,S=2048 -> T=8192)
#define T_TOK 8192
#define H_DIM 1024
#define F_DIM 3584
#define E_NUM 8

// GEMM tiling
#define BM 128
#define BN 128
#define BK 32

typedef __attribute__((ext_vector_type(8))) short bf16x8;
typedef __attribute__((ext_vector_type(4))) float f32x4;
typedef __attribute__((ext_vector_type(4))) uint32_t u32x4;

typedef const __attribute__((address_space(1))) void gv_t;
typedef __attribute__((address_space(3))) void lv_t;

// Async global->LDS, 16B per lane. LDS dest is wave-uniform base + lane*16.
#define GLOAD_LDS16(g, l) \
    __builtin_amdgcn_global_load_lds((gv_t*)(g), (lv_t*)(l), 16, 0, 0)

__device__ __forceinline__ short f2bf(float f) {
    union { float f; uint32_t u; } v; v.f = f;
    uint32_t r = v.u + 0x7fffu + ((v.u >> 16) & 1u);   // RNE bf16
    return (short)(r >> 16);
}

// Pack 2 fp32 -> bf16x2 in ~3 VALU ops via v_perm_b32.
__device__ __forceinline__ uint32_t pack_bf16x2(float a, float b) {
    union { float f; uint32_t u; } ua, ub;
    ua.f = a; ub.f = b;
    return __builtin_amdgcn_perm(ub.u + 0x8000u, ua.u + 0x8000u, 0x07060302u);
}

// ---------------------------------------------------------------------------
// One-shot fp32 -> bf16 conversion of w1, w3, w2, x into workspace.
// ---------------------------------------------------------------------------
__global__ __launch_bounds__(256)
void cvt4_kernel(const float* __restrict__ w1, const float* __restrict__ w3,
                 const float* __restrict__ w2, const float* __restrict__ x,
                 unsigned short* __restrict__ w1b, unsigned short* __restrict__ w3b,
                 unsigned short* __restrict__ w2b, unsigned short* __restrict__ xb) {
    const int z = blockIdx.z;
    const float* src; unsigned short* dst; int n8;
    if (z == 0)      { src = w1; dst = w1b; n8 = (E_NUM * F_DIM * H_DIM) / 8; }
    else if (z == 1) { src = w3; dst = w3b; n8 = (E_NUM * F_DIM * H_DIM) / 8; }
    else if (z == 2) { src = w2; dst = w2b; n8 = (E_NUM * H_DIM * F_DIM) / 8; }
    else             { src = x;  dst = xb;  n8 = (T_TOK * H_DIM) / 8; }

    int idx = blockIdx.x * blockDim.x + threadIdx.x;
    int stride = gridDim.x * blockDim.x;
    for (int i = idx; i < n8; i += stride) {
        const f32x4* p = (const f32x4*)src + (size_t)i * 2;
        f32x4 v0 = p[0], v1 = p[1];
        u32x4 w;
        w[0] = pack_bf16x2(v0[0], v0[1]);
        w[1] = pack_bf16x2(v0[2], v0[3]);
        w[2] = pack_bf16x2(v1[0], v1[1]);
        w[3] = pack_bf16x2(v1[2], v1[3]);
        ((u32x4*)dst)[i] = w;
    }
}

// ---------------------------------------------------------------------------
// Router: one wave per token. fp32 logits (exact), top-2, normalized weights,
// append assignment id a=2t+k to per-expert list.
// ---------------------------------------------------------------------------
__global__ void router_kernel(const float* __restrict__ x,
                              const float* __restrict__ gate_w,
                              float* __restrict__ logits_out,
                              int* __restrict__ counts,
                              int* __restrict__ lists,
                              float* __restrict__ wgt) {
    int wave = (blockIdx.x * blockDim.x + threadIdx.x) >> 6;
    int lane = threadIdx.x & 63;
    if (wave >= T_TOK) return;
    const float* xr = x + (size_t)wave * H_DIM;

    float acc[E_NUM];
    #pragma unroll
    for (int e = 0; e < E_NUM; e++) acc[e] = 0.f;

    for (int i = lane; i < H_DIM; i += 64) {
        float xv = xr[i];
        #pragma unroll
        for (int e = 0; e < E_NUM; e++) acc[e] += xv * gate_w[e * H_DIM + i];
    }
    #pragma unroll
    for (int off = 32; off > 0; off >>= 1) {
        #pragma unroll
        for (int e = 0; e < E_NUM; e++) acc[e] += __shfl_xor(acc[e], off);
    }

    if (lane == 0) {
        int t = wave;
        #pragma unroll
        for (int e = 0; e < E_NUM; e++) logits_out[t * E_NUM + e] = acc[e];
        int i0 = 0; float v0 = acc[0];
        #pragma unroll
        for (int e = 1; e < E_NUM; e++) if (acc[e] > v0) { v0 = acc[e]; i0 = e; }
        int i1 = -1; float v1 = -1e30f;
        #pragma unroll
        for (int e = 0; e < E_NUM; e++) if (e != i0 && acc[e] > v1) { v1 = acc[e]; i1 = e; }
        float e1 = __expf(v1 - v0);
        float inv = 1.f / (1.f + e1);
        int a0 = 2 * t, a1 = 2 * t + 1;
        wgt[a0] = inv;
        wgt[a1] = e1 * inv;
        int p0 = atomicAdd(&counts[i0], 1);
        lists[i0 * T_TOK + p0] = a0;
        int p1 = atomicAdd(&counts[i1], 1);
        lists[i1 * T_TOK + p1] = a1;
    }
}

// ---------------------------------------------------------------------------
// GEMM1: hgate = silu(x @ w1[e]^T) * (x @ w3[e]^T), gathered token rows.
// bf16 inputs; global_load_lds direct staging; double-buffered 2-phase loop.
// ---------------------------------------------------------------------------
__global__ __launch_bounds__(256, 2)
void gemm1_kernel(const unsigned short* __restrict__ xb,
                  const unsigned short* __restrict__ w1b,
                  const unsigned short* __restrict__ w3b,
                  const int* __restrict__ counts,
                  const int* __restrict__ lists,
                  unsigned short* __restrict__ hgate) {
    const int e = blockIdx.z;
    const int count = counts[e];
    const int mbase = blockIdx.y * BM;
    if (mbase >= count) return;
    const int nbase = blockIdx.x * BN;

    __shared__ short As[2][BM * BK];    // 8KB per buffer
    __shared__ short B1s[2][BM * BK];
    __shared__ short B3s[2][BM * BK];

    const int tid = threadIdx.x;
    const int lane = tid & 63;
    const int wid = tid >> 6;
    const int wm = wid >> 1, wn = wid & 1;
    const int lr = lane & 15, lq = lane >> 4;

    // Staging geometry: wave wid covers rows 32*wid..32*wid+31 (two 16-row
    // 1KB chunks). Lane l: row = chunk*16 + (l>>2), k-bytes (l&3)*16.
    const int srow0 = wid * 32 + (lane >> 2);
    const int srow1 = srow0 + 16;
    const int kp8 = (lane & 3) * 8;          // k offset in elems

    const unsigned short *ag0, *ag1;
    {
        int m0 = mbase + srow0; if (m0 >= count) m0 = count - 1;
        int m1 = mbase + srow1; if (m1 >= count) m1 = count - 1;
        ag0 = xb + (size_t)(lists[e * T_TOK + m0] >> 1) * H_DIM + kp8;
        ag1 = xb + (size_t)(lists[e * T_TOK + m1] >> 1) * H_DIM + kp8;
    }
    const unsigned short* b1g0 = w1b + ((size_t)e * F_DIM + nbase + srow0) * H_DIM + kp8;
    const unsigned short* b1g1 = b1g0 + (size_t)16 * H_DIM;
    const unsigned short* b3g0 = w3b + ((size_t)e * F_DIM + nbase + srow0) * H_DIM + kp8;
    const unsigned short* b3g1 = b3g0 + (size_t)16 * H_DIM;

    const int ldsc = wid * 1024;             // wave's chunk base (elems)

    auto stage = [&](int buf) {
        GLOAD_LDS16(ag0,  &As[buf][ldsc]);
        GLOAD_LDS16(ag1,  &As[buf][ldsc + 512]);
        GLOAD_LDS16(b1g0, &B1s[buf][ldsc]);
        GLOAD_LDS16(b1g1, &B1s[buf][ldsc + 512]);
        GLOAD_LDS16(b3g0, &B3s[buf][ldsc]);
        GLOAD_LDS16(b3g1, &B3s[buf][ldsc + 512]);
        ag0 += BK; ag1 += BK;
        b1g0 += BK; b1g1 += BK;
        b3g0 += BK; b3g1 += BK;
    };

    f32x4 acc1[4][4], acc3[4][4];
    #pragma unroll
    for (int i = 0; i < 4; i++)
        #pragma unroll
        for (int j = 0; j < 4; j++) {
            acc1[i][j] = (f32x4){0.f, 0.f, 0.f, 0.f};
            acc3[i][j] = (f32x4){0.f, 0.f, 0.f, 0.f};
        }

    stage(0);
    __syncthreads();                         // buf0 landed (vmcnt drained)

    const int NK = H_DIM / BK;               // 32
    for (int kt = 0; kt < NK; ++kt) {
        const int cur = kt & 1;
        if (kt + 1 < NK) stage(cur ^ 1);     // prefetch next tile (async)

        bf16x8 af[4], b1f[4], b3f[4];
        #pragma unroll
        for (int i = 0; i < 4; i++)
            af[i] = *(const bf16x8*)&As[cur][(wm * 64 + i * 16 + lr) * BK + lq * 8];
        #pragma unroll
        for (int j = 0; j < 4; j++) {
            b1f[j] = *(const bf16x8*)&B1s[cur][(wn * 64 + j * 16 + lr) * BK + lq * 8];
            b3f[j] = *(const bf16x8*)&B3s[cur][(wn * 64 + j * 16 + lr) * BK + lq * 8];
        }
        #pragma unroll
        for (int i = 0; i < 4; i++)
            #pragma unroll
            for (int j = 0; j < 4; j++) {
                acc1[i][j] = __builtin_amdgcn_mfma_f32_16x16x32_bf16(af[i], b1f[j], acc1[i][j], 0, 0, 0);
                acc3[i][j] = __builtin_amdgcn_mfma_f32_16x16x32_bf16(af[i], b3f[j], acc3[i][j], 0, 0, 0);
            }
        __syncthreads();                     // drains vmcnt -> next buf ready
    }

    // Epilogue: silu(g)*u -> bf16, scatter rows by assignment id.
    // C/D layout: col = lane&15, row(within 16) = (lane>>4)*4 + reg
    #pragma unroll
    for (int i = 0; i < 4; i++) {
        #pragma unroll
        for (int rg = 0; rg < 4; rg++) {
            int mm = mbase + wm * 64 + i * 16 + lq * 4 + rg;
            if (mm >= count) continue;
            int a = lists[e * T_TOK + mm];
            unsigned short* hrow = hgate + (size_t)a * F_DIM + nbase;
            #pragma unroll
            for (int j = 0; j < 4; j++) {
                float g = acc1[i][j][rg];
                float u = acc3[i][j][rg];
                float s = (g / (1.f + __expf(-g))) * u;
                hrow[wn * 64 + j * 16 + lr] = (unsigned short)f2bf(s);
            }
        }
    }
}

// ---------------------------------------------------------------------------
// GEMM2: tmp[a] = hgate_row(a) @ w2[e]^T for each assignment a. Plain
// fp32 streaming stores (NO atomics) -- each tmp row is owned by exactly
// one (expert, m) slot, written once. Weighted pair-combine happens in
// combine_kernel.
// ---------------------------------------------------------------------------
__global__ __launch_bounds__(256, 2)
void gemm2_kernel(const unsigned short* __restrict__ hgate,
                  const unsigned short* __restrict__ w2b,
                  const int* __restrict__ counts,
                  const int* __restrict__ lists,
                  float* __restrict__ tmp) {
    const int e = blockIdx.z;
    const int count = counts[e];
    const int mbase = blockIdx.y * BM;
    if (mbase >= count) return;
    const int nbase = blockIdx.x * BN;

    __shared__ short As[2][BM * BK];
    __shared__ short Bs[2][BM * BK];

    const int tid = threadIdx.x;
    const int lane = tid & 63;
    const int wid = tid >> 6;
    const int wm = wid >> 1, wn = wid & 1;
    const int lr = lane & 15, lq = lane >> 4;

    const int srow0 = wid * 32 + (lane >> 2);
    const int srow1 = srow0 + 16;
    const int kp8 = (lane & 3) * 8;

    const unsigned short *ag0, *ag1;
    {
        int m0 = mbase + srow0; if (m0 >= count) m0 = count - 1;
        int m1 = mbase + srow1; if (m1 >= count) m1 = count - 1;
        ag0 = hgate + (size_t)lists[e * T_TOK + m0] * F_DIM + kp8;
        ag1 = hgate + (size_t)lists[e * T_TOK + m1] * F_DIM + kp8;
    }
    const unsigned short* bg0 = w2b + ((size_t)e * H_DIM + nbase + srow0) * F_DIM + kp8;
    const unsigned short* bg1 = bg0 + (size_t)16 * F_DIM;

    const int ldsc = wid * 1024;

    auto stage = [&](int buf) {
        GLOAD_LDS16(ag0, &As[buf][ldsc]);
        GLOAD_LDS16(ag1, &As[buf][ldsc + 512]);
        GLOAD_LDS16(bg0, &Bs[buf][ldsc]);
        GLOAD_LDS16(bg1, &Bs[buf][ldsc + 512]);
        ag0 += BK; ag1 += BK;
        bg0 += BK; bg1 += BK;
    };

    f32x4 acc[4][4];
    #pragma unroll
    for (int i = 0; i < 4; i++)
        #pragma unroll
        for (int j = 0; j < 4; j++) acc[i][j] = (f32x4){0.f, 0.f, 0.f, 0.f};

    stage(0);
    __syncthreads();

    const int NK = F_DIM / BK;               // 112
    for (int kt = 0; kt < NK; ++kt) {
        const int cur = kt & 1;
        if (kt + 1 < NK) stage(cur ^ 1);

        bf16x8 af[4], bfr[4];
        #pragma unroll
        for (int i = 0; i < 4; i++)
            af[i] = *(const bf16x8*)&As[cur][(wm * 64 + i * 16 + lr) * BK + lq * 8];
        #pragma unroll
        for (int j = 0; j < 4; j++)
            bfr[j] = *(const bf16x8*)&Bs[cur][(wn * 64 + j * 16 + lr) * BK + lq * 8];
        #pragma unroll
        for (int i = 0; i < 4; i++)
            #pragma unroll
            for (int j = 0; j < 4; j++)
                acc[i][j] = __builtin_amdgcn_mfma_f32_16x16x32_bf16(af[i], bfr[j], acc[i][j], 0, 0, 0);
        __syncthreads();
    }

    #pragma unroll
    for (int i = 0; i < 4; i++) {
        #pragma unroll
        for (int rg = 0; rg < 4; rg++) {
            int mm = mbase + wm * 64 + i * 16 + lq * 4 + rg;
            if (mm >= count) continue;
            int a = lists[e * T_TOK + mm];
            float* trow = tmp + (size_t)a * H_DIM + nbase;
            #pragma unroll
            for (int j = 0; j < 4; j++)
                trow[wn * 64 + j * 16 + lr] = acc[i][j][rg];
        }
    }
}

// ---------------------------------------------------------------------------
// Combine: out[t] = w[2t]*tmp[2t] + w[2t+1]*tmp[2t+1]. Pure streaming.
// ---------------------------------------------------------------------------
__global__ __launch_bounds__(256)
void combine_kernel(const float* __restrict__ tmp, const float* __restrict__ wgt,
                    float* __restrict__ out) {
    const int n4 = T_TOK * (H_DIM / 4);
    int idx = blockIdx.x * blockDim.x + threadIdx.x;
    int stride = gridDim.x * blockDim.x;
    for (int i = idx; i < n4; i += stride) {
        int t = i >> 8;                      // H_DIM/4 = 256 vec4 per row
        int c = i & 255;
        f32x4 a = ((const f32x4*)tmp)[(size_t)(2 * t) * 256 + c];
        f32x4 b = ((const f32x4*)tmp)[(size_t)(2 * t + 1) * 256 + c];
        float w0 = wgt[2 * t], w1 = wgt[2 * t + 1];
        f32x4 o;
        o[0] = w0 * a[0] + w1 * b[0];
        o[1] = w0 * a[1] + w1 * b[1];
        o[2] = w0 * a[2] + w1 * b[2];
        o[3] = w0 * a[3] + w1 * b[3];
        ((f32x4*)out)[i] = o;
    }
}

// ---------------------------------------------------------------------------
extern "C" void kernel_launch(void* const* d_in, const int* in_sizes, int n_in,
                              void* d_out, int out_size, void* d_ws, size_t ws_size,
                              hipStream_t stream) {
    const float* x      = (const float*)d_in[0];  // [T, H]
    const float* gate_w = (const float*)d_in[1];  // [E, H]
    const float* w1     = (const float*)d_in[2];  // [E, F, H]
    const float* w2     = (const float*)d_in[3];  // [E, H, F]
    const float* w3     = (const float*)d_in[4];  // [E, F, H]

    float* out    = (float*)d_out;                      // [T, H]
    float* logits = out + (size_t)T_TOK * H_DIM;        // [T, E]

    // ws layout: counts[8](pad 1KB) | lists[E][T] | wgt[2T] | hgate[2T][F] bf16
    //            | xb[T][H] bf16 | w1b | w3b | w2b          (~311 MB)
    // tmp[2T][H] fp32 (67.1MB) ALIASES xb+w1b (75.5MB): xb/w1b are dead after
    // gemm1, and stream order serializes gemm1 -> gemm2 -> combine.
    char* ws = (char*)d_ws;
    int*   counts = (int*)(ws + 0);
    int*   lists  = (int*)(ws + 1024);
    float* wgt    = (float*)(ws + 1024 + (size_t)E_NUM * T_TOK * 4);
    unsigned short* hgate =
        (unsigned short*)(ws + 1024 + (size_t)E_NUM * T_TOK * 4 + (size_t)T_TOK * 2 * 4);
    unsigned short* xb  = hgate + (size_t)2 * T_TOK * F_DIM;
    unsigned short* w1b = xb + (size_t)T_TOK * H_DIM;
    unsigned short* w3b = w1b + (size_t)E_NUM * F_DIM * H_DIM;
    unsigned short* w2b = w3b + (size_t)E_NUM * F_DIM * H_DIM;
    float* tmp = (float*)xb;                 // [2T, H] fp32, aliases xb/w1b

    hipMemsetAsync(counts, 0, E_NUM * sizeof(int), stream);

    cvt4_kernel<<<dim3(1024, 1, 4), 256, 0, stream>>>(w1, w3, w2, x, w1b, w3b, w2b, xb);

    router_kernel<<<T_TOK / 4, 256, 0, stream>>>(x, gate_w, logits, counts, lists, wgt);

    gemm1_kernel<<<dim3(F_DIM / BN, T_TOK / BM, E_NUM), 256, 0, stream>>>(
        xb, w1b, w3b, counts, lists, hgate);

    gemm2_kernel<<<dim3(H_DIM / BN, T_TOK / BM, E_NUM), 256, 0, stream>>>(
        hgate, w2b, counts, lists, tmp);

    combine_kernel<<<2048, 256, 0, stream>>>(tmp, wgt, out);
}